// Round 1
// baseline (559.806 us; speedup 1.0000x reference)
//
#include <hip/hip_runtime.h>

#define N_NODES 50000
#define N_EDGES 800000
#define F 64  // feature dim for both layers (F_IN = HID = 64)

// One 64-lane group per edge: lane l handles feature l.
// Gather feat[src] (coalesced) and atomicAdd into sum[dst] (coalesced across lanes).
__global__ __launch_bounds__(256) void sage_scatter(
    const float* __restrict__ feat,   // [N,64]
    const int*   __restrict__ src,    // [E]
    const int*   __restrict__ dst,    // [E]
    float*       __restrict__ sum,    // [N,64] accumulator (pre-zeroed)
    float*       __restrict__ cnt,    // [N] degree accumulator (pre-zeroed), may be null
    int E) {
  int idx  = blockIdx.x * blockDim.x + threadIdx.x;
  int e    = idx >> 6;
  int lane = idx & 63;
  if (e >= E) return;
  int s = src[e];
  int d = dst[e];
  atomicAdd(&sum[d * F + lane], feat[s * F + lane]);
  if (cnt != nullptr && lane == 0) atomicAdd(&cnt[d], 1.0f);
}

// 4 nodes per 256-thread block. W (128x64 = 32KB) staged in LDS once per block.
// Thread (g, j): node = blockIdx.x*4 + g, output feature j.
// row[g][0:64] = self features, row[g][64:128] = mean-aggregated neighbor features.
__global__ __launch_bounds__(256) void sage_linear(
    const float* __restrict__ xin,   // [N,64] self features
    const float* __restrict__ sum,   // [N,64] neighbor feature sums
    const float* __restrict__ cnt,   // [N]
    const float* __restrict__ W,     // [128,64] row-major
    const float* __restrict__ b,     // [64]
    float*       __restrict__ out,   // [N,64]
    int do_relu) {
  __shared__ float Ws[128 * 64];
  __shared__ float row[4][128];
  int tid = threadIdx.x;
  for (int i = tid; i < 128 * 64; i += 256) Ws[i] = W[i];

  int g = tid >> 6;    // node within block (0..3)
  int j = tid & 63;    // output feature
  int n = blockIdx.x * 4 + g;
  if (n < N_NODES) {
    float inv = 1.0f / fmaxf(cnt[n], 1.0f);
    row[g][j]      = xin[n * F + j];
    row[g][64 + j] = sum[n * F + j] * inv;
  }
  __syncthreads();
  if (n >= N_NODES) return;

  float acc = b[j];
  // k broadcast across the 64 lanes of a node-group (no bank conflict);
  // Ws[k*64+j]: stride-1 in j -> 2 lanes/bank, free on CDNA4.
  #pragma unroll 8
  for (int k = 0; k < 128; ++k) acc += row[g][k] * Ws[k * 64 + j];
  if (do_relu) acc = fmaxf(acc, 0.0f);
  out[n * F + j] = acc;
}

extern "C" void kernel_launch(void* const* d_in, const int* in_sizes, int n_in,
                              void* d_out, int out_size, void* d_ws, size_t ws_size,
                              hipStream_t stream) {
  const float* x  = (const float*)d_in[0];
  const int*   ei = (const int*)d_in[1];   // [2,E]: row 0 = src, row 1 = dst
  const float* W1 = (const float*)d_in[2];
  const float* b1 = (const float*)d_in[3];
  const float* W2 = (const float*)d_in[4];
  const float* b2 = (const float*)d_in[5];
  float* out = (float*)d_out;

  // workspace layout (floats): s1[N*64] | s2[N*64] | cnt[N] | h1[N*64]
  float* s1  = (float*)d_ws;
  float* s2  = s1 + (size_t)N_NODES * F;
  float* cnt = s2 + (size_t)N_NODES * F;
  float* h1  = cnt + N_NODES;

  // ws is re-poisoned to 0xAA before every launch: zero the accumulators.
  size_t zero_bytes = (size_t)(2 * N_NODES * F + N_NODES) * sizeof(float);
  hipMemsetAsync(d_ws, 0, zero_bytes, stream);

  const int* src = ei;
  const int* dst = ei + N_EDGES;

  dim3 blk(256);
  dim3 grd_scatter((unsigned)(((size_t)N_EDGES * 64 + 255) / 256));
  dim3 grd_linear((N_NODES + 3) / 4);

  // Layer 1
  sage_scatter<<<grd_scatter, blk, 0, stream>>>(x, src, dst, s1, cnt, N_EDGES);
  sage_linear<<<grd_linear, blk, 0, stream>>>(x, s1, cnt, W1, b1, h1, 1);
  // Layer 2 (degree counts unchanged)
  sage_scatter<<<grd_scatter, blk, 0, stream>>>(h1, src, dst, s2, nullptr, N_EDGES);
  sage_linear<<<grd_linear, blk, 0, stream>>>(h1, s2, cnt, W2, b2, out, 0);
}

// Round 2
// 346.122 us; speedup vs baseline: 1.6174x; 1.6174x over previous
//
#include <hip/hip_runtime.h>

#define N_NODES 50000
#define N_EDGES 800000
#define F 64
#define SCAN_B 256
#define NB_SCAN ((N_NODES + SCAN_B - 1) / SCAN_B)   // 196

// ---------- CSR build ----------
__global__ __launch_bounds__(256) void hist_kernel(
    const int* __restrict__ dst, int* __restrict__ deg, int E) {
  int e = blockIdx.x * blockDim.x + threadIdx.x;
  if (e < E) atomicAdd(&deg[dst[e]], 1);
}

// block-local exclusive scan of deg -> row_start, block totals -> bsums
__global__ __launch_bounds__(SCAN_B) void scan1_kernel(
    const int* __restrict__ deg, int* __restrict__ row_start, int* __restrict__ bsums) {
  __shared__ int s[SCAN_B];
  int t = threadIdx.x;
  int i = blockIdx.x * SCAN_B + t;
  int v = (i < N_NODES) ? deg[i] : 0;
  s[t] = v;
  __syncthreads();
  for (int off = 1; off < SCAN_B; off <<= 1) {
    int add = (t >= off) ? s[t - off] : 0;
    __syncthreads();
    s[t] += add;
    __syncthreads();
  }
  if (i < N_NODES) row_start[i] = s[t] - v;          // exclusive, block-local
  if (t == SCAN_B - 1) bsums[blockIdx.x] = s[t];     // block total
}

// exclusive scan of the 196 block sums (single block)
__global__ __launch_bounds__(SCAN_B) void scan2_kernel(int* __restrict__ bsums) {
  __shared__ int s[SCAN_B];
  int t = threadIdx.x;
  int v = (t < NB_SCAN) ? bsums[t] : 0;
  s[t] = v;
  __syncthreads();
  for (int off = 1; off < SCAN_B; off <<= 1) {
    int add = (t >= off) ? s[t - off] : 0;
    __syncthreads();
    s[t] += add;
    __syncthreads();
  }
  if (t < NB_SCAN) bsums[t] = s[t] - v;
}

// add block offsets; init cursor = row_start
__global__ __launch_bounds__(SCAN_B) void scan3_kernel(
    int* __restrict__ row_start, const int* __restrict__ bsums, int* __restrict__ cursor) {
  int i = blockIdx.x * SCAN_B + threadIdx.x;
  if (i < N_NODES) {
    int rs = row_start[i] + bsums[blockIdx.x];
    row_start[i] = rs;
    cursor[i] = rs;
  }
}

// counting-sort pass: place src index of each edge into its dst bucket
__global__ __launch_bounds__(256) void scatter_idx_kernel(
    const int* __restrict__ src, const int* __restrict__ dst,
    int* __restrict__ cursor, int* __restrict__ edge_src, int E) {
  int e = blockIdx.x * blockDim.x + threadIdx.x;
  if (e < E) {
    int pos = atomicAdd(&cursor[dst[e]], 1);
    edge_src[pos] = src[e];
  }
}

// ---------- pull-mode mean aggregation: one wave per node ----------
__global__ __launch_bounds__(256) void sage_aggregate(
    const float* __restrict__ feat,      // [N,64]
    const int*   __restrict__ row_start, // [N]
    const int*   __restrict__ deg,       // [N]
    const int*   __restrict__ edge_src,  // [E] sorted by dst
    float*       __restrict__ mean) {    // [N,64]
  int idx  = blockIdx.x * blockDim.x + threadIdx.x;
  int n    = idx >> 6;
  int lane = idx & 63;
  if (n >= N_NODES) return;
  int start = row_start[n];
  int d     = deg[n];
  float acc = 0.0f;
  for (int base = 0; base < d; base += 64) {
    int rem  = d - base;
    int nk   = rem < 64 ? rem : 64;
    int sidx = 0;
    if (base + lane < d) sidx = edge_src[start + base + lane];  // coalesced
    for (int u = 0; u < nk; ++u) {
      int s = __shfl(sidx, u);
      acc += feat[(size_t)s * F + lane];   // 256B coalesced gather, cache-resident
    }
  }
  mean[(size_t)n * F + lane] = (d > 0) ? acc / (float)d : 0.0f;
}

// ---------- linear: out[n] = [xin[n] || mean[n]] @ W + b, 32 nodes/block ----------
__global__ __launch_bounds__(256) void sage_linear(
    const float* __restrict__ xin,   // [N,64]
    const float* __restrict__ mean,  // [N,64]
    const float* __restrict__ W,     // [128,64] row-major
    const float* __restrict__ b,     // [64]
    float*       __restrict__ out,   // [N,64]
    int do_relu) {
  __shared__ float Ws[128 * 64];     // 32 KB
  __shared__ float row[32][128];     // 16 KB
  int t = threadIdx.x;
  int g = t >> 6;                    // wave id 0..3
  int j = t & 63;                    // output feature
  int base = blockIdx.x * 32;

  for (int i = t; i < 128 * 64; i += 256) Ws[i] = W[i];
  #pragma unroll
  for (int rep = 0; rep < 8; ++rep) {
    int i = rep * 4 + g;             // local node 0..31
    int n = base + i;
    if (n < N_NODES) {
      row[i][j]      = xin[(size_t)n * F + j];
      row[i][64 + j] = mean[(size_t)n * F + j];
    }
  }
  __syncthreads();

  float bj = b[j];
  float acc[8];
  #pragma unroll
  for (int u = 0; u < 8; ++u) acc[u] = bj;

  // wave g handles local nodes g*8 .. g*8+7; row reads are wave-uniform (broadcast)
  #pragma unroll 4
  for (int k4 = 0; k4 < 32; ++k4) {
    float4 r[8];
    #pragma unroll
    for (int u = 0; u < 8; ++u)
      r[u] = *(const float4*)&row[g * 8 + u][k4 * 4];
    #pragma unroll
    for (int kk = 0; kk < 4; ++kk) {
      float w = Ws[(k4 * 4 + kk) * 64 + j];
      #pragma unroll
      for (int u = 0; u < 8; ++u)
        acc[u] += ((const float*)&r[u])[kk] * w;
    }
  }

  #pragma unroll
  for (int u = 0; u < 8; ++u) {
    int n = base + g * 8 + u;
    if (n < N_NODES) {
      float v = acc[u];
      if (do_relu) v = fmaxf(v, 0.0f);
      out[(size_t)n * F + j] = v;
    }
  }
}

extern "C" void kernel_launch(void* const* d_in, const int* in_sizes, int n_in,
                              void* d_out, int out_size, void* d_ws, size_t ws_size,
                              hipStream_t stream) {
  const float* x  = (const float*)d_in[0];
  const int*   ei = (const int*)d_in[1];   // [2,E]: row 0 = src, row 1 = dst
  const float* W1 = (const float*)d_in[2];
  const float* b1 = (const float*)d_in[3];
  const float* W2 = (const float*)d_in[4];
  const float* b2 = (const float*)d_in[5];
  float* out = (float*)d_out;

  const int* src = ei;
  const int* dst = ei + N_EDGES;

  // workspace layout (4-byte units), padded for 16B alignment:
  //   deg[50048] | row_start[50048] | cursor[50048] | bsums[256] |
  //   edge_src[800000] | mean[N*64] | h1[N*64]
  int* deg       = (int*)d_ws;
  int* row_start = deg + 50048;
  int* cursor    = row_start + 50048;
  int* bsums     = cursor + 50048;
  int* edge_src  = bsums + 256;            // int offset 150400
  float* mean    = (float*)(edge_src + N_EDGES);   // offset 950400 (16B aligned)
  float* h1      = mean + (size_t)N_NODES * F;

  // zero only the degree histogram (ws is poisoned 0xAA each call)
  hipMemsetAsync(deg, 0, 50048 * sizeof(int), stream);

  dim3 blk(256);
  dim3 grd_e((N_EDGES + 255) / 256);        // 3125
  dim3 grd_scan(NB_SCAN);                   // 196
  dim3 grd_agg(((size_t)N_NODES * 64 + 255) / 256);  // 12500
  dim3 grd_lin((N_NODES + 31) / 32);        // 1563

  // CSR build (once; graph shared by both layers)
  hist_kernel<<<grd_e, blk, 0, stream>>>(dst, deg, N_EDGES);
  scan1_kernel<<<grd_scan, blk, 0, stream>>>(deg, row_start, bsums);
  scan2_kernel<<<1, blk, 0, stream>>>(bsums);
  scan3_kernel<<<grd_scan, blk, 0, stream>>>(row_start, bsums, cursor);
  scatter_idx_kernel<<<grd_e, blk, 0, stream>>>(src, dst, cursor, edge_src, N_EDGES);

  // Layer 1
  sage_aggregate<<<grd_agg, blk, 0, stream>>>(x, row_start, deg, edge_src, mean);
  sage_linear<<<grd_lin, blk, 0, stream>>>(x, mean, W1, b1, h1, 1);
  // Layer 2
  sage_aggregate<<<grd_agg, blk, 0, stream>>>(h1, row_start, deg, edge_src, mean);
  sage_linear<<<grd_lin, blk, 0, stream>>>(h1, mean, W2, b2, out, 0);
}

// Round 3
// 299.452 us; speedup vs baseline: 1.8694x; 1.1559x over previous
//
#include <hip/hip_runtime.h>

#define N_NODES 50000
#define N_EDGES 800000
#define F 64
#define SCAN_B 256
#define NB_SCAN ((N_NODES + SCAN_B - 1) / SCAN_B)   // 196

// ---------- CSR build ----------
__global__ __launch_bounds__(256) void hist_kernel(
    const int* __restrict__ dst, int* __restrict__ deg, int E) {
  int e = blockIdx.x * blockDim.x + threadIdx.x;
  if (e < E) atomicAdd(&deg[dst[e]], 1);
}

// block-local exclusive scan of deg -> row_start, block totals -> bsums
__global__ __launch_bounds__(SCAN_B) void scan1_kernel(
    const int* __restrict__ deg, int* __restrict__ row_start, int* __restrict__ bsums) {
  __shared__ int s[SCAN_B];
  int t = threadIdx.x;
  int i = blockIdx.x * SCAN_B + t;
  int v = (i < N_NODES) ? deg[i] : 0;
  s[t] = v;
  __syncthreads();
  for (int off = 1; off < SCAN_B; off <<= 1) {
    int add = (t >= off) ? s[t - off] : 0;
    __syncthreads();
    s[t] += add;
    __syncthreads();
  }
  if (i < N_NODES) row_start[i] = s[t] - v;          // exclusive, block-local
  if (t == SCAN_B - 1) bsums[blockIdx.x] = s[t];     // block total
}

// exclusive scan of the 196 block sums (single block)
__global__ __launch_bounds__(SCAN_B) void scan2_kernel(int* __restrict__ bsums) {
  __shared__ int s[SCAN_B];
  int t = threadIdx.x;
  int v = (t < NB_SCAN) ? bsums[t] : 0;
  s[t] = v;
  __syncthreads();
  for (int off = 1; off < SCAN_B; off <<= 1) {
    int add = (t >= off) ? s[t - off] : 0;
    __syncthreads();
    s[t] += add;
    __syncthreads();
  }
  if (t < NB_SCAN) bsums[t] = s[t] - v;
}

// add block offsets; init cursor = row_start
__global__ __launch_bounds__(SCAN_B) void scan3_kernel(
    int* __restrict__ row_start, const int* __restrict__ bsums, int* __restrict__ cursor) {
  int i = blockIdx.x * SCAN_B + threadIdx.x;
  if (i < N_NODES) {
    int rs = row_start[i] + bsums[blockIdx.x];
    row_start[i] = rs;
    cursor[i] = rs;
  }
}

// counting-sort pass: place src index of each edge into its dst bucket
__global__ __launch_bounds__(256) void scatter_idx_kernel(
    const int* __restrict__ src, const int* __restrict__ dst,
    int* __restrict__ cursor, int* __restrict__ edge_src, int E) {
  int e = blockIdx.x * blockDim.x + threadIdx.x;
  if (e < E) {
    int pos = atomicAdd(&cursor[dst[e]], 1);
    edge_src[pos] = src[e];
  }
}

// ---------- pull-mode mean aggregation ----------
// One wave per node. Wave split into 4 groups of 16 lanes: group g handles
// edge (base+g), lane-quad q loads feat row float4 #q (16 lanes x 16B = 256B row).
// 4 independent row-gathers in flight per iteration (8 with unroll 2).
__global__ __launch_bounds__(256) void sage_aggregate(
    const float4* __restrict__ feat4,     // [N,16] float4 view of [N,64]
    const int*    __restrict__ row_start, // [N]
    const int*    __restrict__ deg,       // [N]
    const int*    __restrict__ edge_src,  // [E] sorted by dst
    float4*       __restrict__ mean4) {   // [N,16] float4 view
  int idx  = blockIdx.x * blockDim.x + threadIdx.x;
  int n    = idx >> 6;
  int lane = idx & 63;
  if (n >= N_NODES) return;
  int g = lane >> 4;     // edge sub-slot 0..3
  int q = lane & 15;     // feature quad 0..15
  int start = row_start[n];
  int d     = deg[n];
  float4 acc = make_float4(0.f, 0.f, 0.f, 0.f);
  #pragma unroll 2
  for (int base = 0; base < d; base += 4) {
    int e = base + g;
    if (e < d) {
      int s = edge_src[start + e];                 // 16 lanes share one addr
      float4 v = feat4[(size_t)s * 16 + q];        // 256B coalesced row gather
      acc.x += v.x; acc.y += v.y; acc.z += v.z; acc.w += v.w;
    }
  }
  // fold the 4 edge-groups: lanes l, l^16, l^32, l^48 hold same feature quad
  acc.x += __shfl_xor(acc.x, 16); acc.y += __shfl_xor(acc.y, 16);
  acc.z += __shfl_xor(acc.z, 16); acc.w += __shfl_xor(acc.w, 16);
  acc.x += __shfl_xor(acc.x, 32); acc.y += __shfl_xor(acc.y, 32);
  acc.z += __shfl_xor(acc.z, 32); acc.w += __shfl_xor(acc.w, 32);
  if (lane < 16) {
    float inv = (d > 0) ? 1.0f / (float)d : 0.0f;
    acc.x *= inv; acc.y *= inv; acc.z *= inv; acc.w *= inv;
    mean4[(size_t)n * 16 + q] = acc;               // 256B coalesced store
  }
}

// ---------- linear: out[n] = [xin[n] || mean[n]] @ W + b, 32 nodes/block ----------
__global__ __launch_bounds__(256) void sage_linear(
    const float* __restrict__ xin,   // [N,64]
    const float* __restrict__ mean,  // [N,64]
    const float* __restrict__ W,     // [128,64] row-major
    const float* __restrict__ b,     // [64]
    float*       __restrict__ out,   // [N,64]
    int do_relu) {
  __shared__ float Ws[128 * 64];     // 32 KB
  __shared__ float row[32][128];     // 16 KB
  int t = threadIdx.x;
  int g = t >> 6;                    // wave id 0..3
  int j = t & 63;                    // output feature
  int base = blockIdx.x * 32;

  for (int i = t; i < 128 * 64; i += 256) Ws[i] = W[i];
  #pragma unroll
  for (int rep = 0; rep < 8; ++rep) {
    int i = rep * 4 + g;             // local node 0..31
    int n = base + i;
    if (n < N_NODES) {
      row[i][j]      = xin[(size_t)n * F + j];
      row[i][64 + j] = mean[(size_t)n * F + j];
    }
  }
  __syncthreads();

  float bj = b[j];
  float acc[8];
  #pragma unroll
  for (int u = 0; u < 8; ++u) acc[u] = bj;

  #pragma unroll 4
  for (int k4 = 0; k4 < 32; ++k4) {
    float4 r[8];
    #pragma unroll
    for (int u = 0; u < 8; ++u)
      r[u] = *(const float4*)&row[g * 8 + u][k4 * 4];
    #pragma unroll
    for (int kk = 0; kk < 4; ++kk) {
      float w = Ws[(k4 * 4 + kk) * 64 + j];
      #pragma unroll
      for (int u = 0; u < 8; ++u)
        acc[u] += ((const float*)&r[u])[kk] * w;
    }
  }

  #pragma unroll
  for (int u = 0; u < 8; ++u) {
    int n = base + g * 8 + u;
    if (n < N_NODES) {
      float v = acc[u];
      if (do_relu) v = fmaxf(v, 0.0f);
      out[(size_t)n * F + j] = v;
    }
  }
}

extern "C" void kernel_launch(void* const* d_in, const int* in_sizes, int n_in,
                              void* d_out, int out_size, void* d_ws, size_t ws_size,
                              hipStream_t stream) {
  const float* x  = (const float*)d_in[0];
  const int*   ei = (const int*)d_in[1];   // [2,E]: row 0 = src, row 1 = dst
  const float* W1 = (const float*)d_in[2];
  const float* b1 = (const float*)d_in[3];
  const float* W2 = (const float*)d_in[4];
  const float* b2 = (const float*)d_in[5];
  float* out = (float*)d_out;

  const int* src = ei;
  const int* dst = ei + N_EDGES;

  // workspace layout (4-byte units), padded for 16B alignment:
  //   deg[50048] | row_start[50048] | cursor[50048] | bsums[256] |
  //   edge_src[800000] | mean[N*64] | h1[N*64]
  int* deg       = (int*)d_ws;
  int* row_start = deg + 50048;
  int* cursor    = row_start + 50048;
  int* bsums     = cursor + 50048;
  int* edge_src  = bsums + 256;
  float* mean    = (float*)(edge_src + N_EDGES);
  float* h1      = mean + (size_t)N_NODES * F;

  hipMemsetAsync(deg, 0, 50048 * sizeof(int), stream);

  dim3 blk(256);
  dim3 grd_e((N_EDGES + 255) / 256);                 // 3125
  dim3 grd_scan(NB_SCAN);                            // 196
  dim3 grd_agg(((size_t)N_NODES * 64 + 255) / 256);  // 12500
  dim3 grd_lin((N_NODES + 31) / 32);                 // 1563

  // CSR build (once; graph shared by both layers)
  hist_kernel<<<grd_e, blk, 0, stream>>>(dst, deg, N_EDGES);
  scan1_kernel<<<grd_scan, blk, 0, stream>>>(deg, row_start, bsums);
  scan2_kernel<<<1, blk, 0, stream>>>(bsums);
  scan3_kernel<<<grd_scan, blk, 0, stream>>>(row_start, bsums, cursor);
  scatter_idx_kernel<<<grd_e, blk, 0, stream>>>(src, dst, cursor, edge_src, N_EDGES);

  // Layer 1
  sage_aggregate<<<grd_agg, blk, 0, stream>>>(
      (const float4*)x, row_start, deg, edge_src, (float4*)mean);
  sage_linear<<<grd_lin, blk, 0, stream>>>(x, mean, W1, b1, h1, 1);
  // Layer 2
  sage_aggregate<<<grd_agg, blk, 0, stream>>>(
      (const float4*)h1, row_start, deg, edge_src, (float4*)mean);
  sage_linear<<<grd_lin, blk, 0, stream>>>(h1, mean, W2, b2, out, 0);
}

// Round 4
// 245.375 us; speedup vs baseline: 2.2814x; 1.2204x over previous
//
#include <hip/hip_runtime.h>

#define N_NODES 50000
#define N_EDGES 800000
#define F 64
#define NBUCK 196        // coarse buckets: dst >> 8  (50000/256 -> 0..195)
#define CHUNK 6144       // edges per partition workgroup
#define NWG1 ((N_EDGES + CHUNK - 1) / CHUNK)   // 131
#define CAP2 8192        // pass-2 LDS capacity (mean bucket 4082, sigma 64)

// ---------- A: coarse histogram (LDS-staged; 196 global atomics per wg) ----------
__global__ __launch_bounds__(256) void coarse_hist(
    const int* __restrict__ dst, int* __restrict__ ccount) {
  __shared__ int h[256];
  int t = threadIdx.x;
  h[t] = 0; __syncthreads();
  for (int i = blockIdx.x * blockDim.x + t; i < N_EDGES; i += gridDim.x * blockDim.x)
    atomicAdd(&h[dst[i] >> 8], 1);
  __syncthreads();
  if (h[t] > 0) atomicAdd(&ccount[t], h[t]);
}

// ---------- B: scan of 196 bucket counts -> cstart (exclusive) + cursor init ----------
__global__ __launch_bounds__(256) void coarse_scan(
    const int* __restrict__ ccount, int* __restrict__ cstart, int* __restrict__ ccursor) {
  __shared__ int s[256];
  int t = threadIdx.x;
  int v = ccount[t];                 // slots >= NBUCK are zero (memset covers 256)
  s[t] = v; __syncthreads();
  for (int off = 1; off < 256; off <<= 1) {
    int a = (t >= off) ? s[t - off] : 0;
    __syncthreads();
    s[t] += a;
    __syncthreads();
  }
  cstart[t]  = s[t] - v;             // cstart[196] = E falls out naturally (empty buckets)
  ccursor[t] = s[t] - v;
}

// ---------- C: partition edges into coarse buckets, all global writes coalesced ----------
__global__ __launch_bounds__(256) void partition_coarse(
    const int* __restrict__ src, const int* __restrict__ dst,
    int* __restrict__ ccursor, unsigned* __restrict__ ebuf) {
  __shared__ int hist[256], scn[256], gbase[256], lcur[256];
  __shared__ unsigned stage[CHUNK];          // 24 KB
  int t  = threadIdx.x;
  int e0 = blockIdx.x * CHUNK;
  int cnt = N_EDGES - e0; if (cnt > CHUNK) cnt = CHUNK;

  hist[t] = 0; __syncthreads();
  for (int i = t; i < cnt; i += 256) atomicAdd(&hist[dst[e0 + i] >> 8], 1);
  __syncthreads();

  int v = hist[t];
  scn[t] = v; __syncthreads();
  for (int off = 1; off < 256; off <<= 1) {
    int a = (t >= off) ? scn[t - off] : 0;
    __syncthreads();
    scn[t] += a;
    __syncthreads();
  }
  int excl = scn[t] - v;
  scn[t]  = excl;                            // scn becomes lscan (own-slot write)
  lcur[t] = excl;
  if (v > 0) gbase[t] = atomicAdd(&ccursor[t], v);   // reserve global space
  __syncthreads();

  // stage packed edges in bucket-major order: (bucket<<24) | (dst&255)<<16 | src
  for (int i = t; i < cnt; i += 256) {
    int d = dst[e0 + i], s = src[e0 + i];
    int b = d >> 8;
    int p = atomicAdd(&lcur[b], 1);
    stage[p] = ((unsigned)b << 24) | ((unsigned)(d & 255) << 16) | (unsigned)s;
  }
  __syncthreads();

  // coalesced write-out: consecutive staged indices -> consecutive global slots per bucket
  for (int i = t; i < cnt; i += 256) {
    unsigned e = stage[i];
    int b = e >> 24;
    ebuf[gbase[b] + (i - scn[b])] = e;
  }
}

// ---------- D: per-bucket counting sort by node; emits edge_src + row_start + deg ----------
__global__ __launch_bounds__(256) void bucket_sort(
    const unsigned* __restrict__ ebuf, const int* __restrict__ cstart,
    int* __restrict__ edge_src, int* __restrict__ row_start, int* __restrict__ deg) {
  __shared__ int lhist[256], lscan[256], lcur[256];
  __shared__ unsigned short srt[CAP2];       // 16 KB
  int b = blockIdx.x, t = threadIdx.x;
  int s0 = cstart[b], s1 = cstart[b + 1];
  int cnt = s1 - s0;

  lhist[t] = 0; __syncthreads();
  for (int i = t; i < cnt; i += 256) atomicAdd(&lhist[(ebuf[s0 + i] >> 16) & 255], 1);
  __syncthreads();

  int v = lhist[t];
  lscan[t] = v; __syncthreads();
  for (int off = 1; off < 256; off <<= 1) {
    int a = (t >= off) ? lscan[t - off] : 0;
    __syncthreads();
    lscan[t] += a;
    __syncthreads();
  }
  lscan[t] -= v;                             // exclusive (own-slot)
  lcur[t] = lscan[t];
  __syncthreads();

  for (int i = t; i < cnt; i += 256) {
    unsigned e = ebuf[s0 + i];
    int p = atomicAdd(&lcur[(e >> 16) & 255], 1);
    srt[p] = (unsigned short)(e & 0xFFFFu);
  }
  __syncthreads();

  for (int i = t; i < cnt; i += 256) edge_src[s0 + i] = (int)srt[i];  // coalesced

  int n = b * 256 + t;
  if (n < N_NODES) { row_start[n] = s0 + lscan[t]; deg[n] = v; }
}

// ---------- pull-mode mean aggregation (unchanged from R3) ----------
__global__ __launch_bounds__(256) void sage_aggregate(
    const float4* __restrict__ feat4,     // [N,16] float4 view of [N,64]
    const int*    __restrict__ row_start, // [N]
    const int*    __restrict__ deg,       // [N]
    const int*    __restrict__ edge_src,  // [E] sorted by dst
    float4*       __restrict__ mean4) {   // [N,16] float4 view
  int idx  = blockIdx.x * blockDim.x + threadIdx.x;
  int n    = idx >> 6;
  int lane = idx & 63;
  if (n >= N_NODES) return;
  int g = lane >> 4;     // edge sub-slot 0..3
  int q = lane & 15;     // feature quad 0..15
  int start = row_start[n];
  int d     = deg[n];
  float4 acc = make_float4(0.f, 0.f, 0.f, 0.f);
  #pragma unroll 2
  for (int base = 0; base < d; base += 4) {
    int e = base + g;
    if (e < d) {
      int s = edge_src[start + e];
      float4 v = feat4[(size_t)s * 16 + q];
      acc.x += v.x; acc.y += v.y; acc.z += v.z; acc.w += v.w;
    }
  }
  acc.x += __shfl_xor(acc.x, 16); acc.y += __shfl_xor(acc.y, 16);
  acc.z += __shfl_xor(acc.z, 16); acc.w += __shfl_xor(acc.w, 16);
  acc.x += __shfl_xor(acc.x, 32); acc.y += __shfl_xor(acc.y, 32);
  acc.z += __shfl_xor(acc.z, 32); acc.w += __shfl_xor(acc.w, 32);
  if (lane < 16) {
    float inv = (d > 0) ? 1.0f / (float)d : 0.0f;
    acc.x *= inv; acc.y *= inv; acc.z *= inv; acc.w *= inv;
    mean4[(size_t)n * 16 + q] = acc;
  }
}

// ---------- linear: out[n] = [xin[n] || mean[n]] @ W + b (unchanged from R3) ----------
__global__ __launch_bounds__(256) void sage_linear(
    const float* __restrict__ xin, const float* __restrict__ mean,
    const float* __restrict__ W, const float* __restrict__ b,
    float* __restrict__ out, int do_relu) {
  __shared__ float Ws[128 * 64];
  __shared__ float row[32][128];
  int t = threadIdx.x;
  int g = t >> 6;
  int j = t & 63;
  int base = blockIdx.x * 32;

  for (int i = t; i < 128 * 64; i += 256) Ws[i] = W[i];
  #pragma unroll
  for (int rep = 0; rep < 8; ++rep) {
    int i = rep * 4 + g;
    int n = base + i;
    if (n < N_NODES) {
      row[i][j]      = xin[(size_t)n * F + j];
      row[i][64 + j] = mean[(size_t)n * F + j];
    }
  }
  __syncthreads();

  float bj = b[j];
  float acc[8];
  #pragma unroll
  for (int u = 0; u < 8; ++u) acc[u] = bj;

  #pragma unroll 4
  for (int k4 = 0; k4 < 32; ++k4) {
    float4 r[8];
    #pragma unroll
    for (int u = 0; u < 8; ++u)
      r[u] = *(const float4*)&row[g * 8 + u][k4 * 4];
    #pragma unroll
    for (int kk = 0; kk < 4; ++kk) {
      float w = Ws[(k4 * 4 + kk) * 64 + j];
      #pragma unroll
      for (int u = 0; u < 8; ++u)
        acc[u] += ((const float*)&r[u])[kk] * w;
    }
  }

  #pragma unroll
  for (int u = 0; u < 8; ++u) {
    int n = base + g * 8 + u;
    if (n < N_NODES) {
      float v = acc[u];
      if (do_relu) v = fmaxf(v, 0.0f);
      out[(size_t)n * F + j] = v;
    }
  }
}

extern "C" void kernel_launch(void* const* d_in, const int* in_sizes, int n_in,
                              void* d_out, int out_size, void* d_ws, size_t ws_size,
                              hipStream_t stream) {
  const float* x  = (const float*)d_in[0];
  const int*   ei = (const int*)d_in[1];   // [2,E]: row 0 = src, row 1 = dst
  const float* W1 = (const float*)d_in[2];
  const float* b1 = (const float*)d_in[3];
  const float* W2 = (const float*)d_in[4];
  const float* b2 = (const float*)d_in[5];
  float* out = (float*)d_out;

  const int* src = ei;
  const int* dst = ei + N_EDGES;

  // ws layout (int offsets):
  //   ccount@0[256] | cstart@512[257] | ccursor@1024[256] | deg@1536[50048] |
  //   row_start@51584[50048] | edge_src@101632[800000] |
  //   ebuf@901632[800000]  (ALIASES mean — ebuf dead before first aggregate) |
  //   mean@901632[N*64] | h1@4101632[N*64]        total 7,301,632 ints = 29.2 MB
  int* wsi       = (int*)d_ws;
  int* ccount    = wsi;
  int* cstart    = wsi + 512;
  int* ccursor   = wsi + 1024;
  int* deg       = wsi + 1536;
  int* row_start = wsi + 51584;
  int* edge_src  = wsi + 101632;
  unsigned* ebuf = (unsigned*)(wsi + 901632);
  float* mean    = (float*)(wsi + 901632);
  float* h1      = (float*)(wsi + 4101632);

  hipMemsetAsync(ccount, 0, 256 * sizeof(int), stream);

  dim3 blk(256);
  // CSR build: coarse hist -> scan -> partition -> per-bucket sort
  coarse_hist<<<256, blk, 0, stream>>>(dst, ccount);
  coarse_scan<<<1, blk, 0, stream>>>(ccount, cstart, ccursor);
  partition_coarse<<<NWG1, blk, 0, stream>>>(src, dst, ccursor, ebuf);
  bucket_sort<<<NBUCK, blk, 0, stream>>>(ebuf, cstart, edge_src, row_start, deg);

  dim3 grd_agg((unsigned)(((size_t)N_NODES * 64 + 255) / 256));  // 12500
  dim3 grd_lin((N_NODES + 31) / 32);                             // 1563

  // Layer 1
  sage_aggregate<<<grd_agg, blk, 0, stream>>>(
      (const float4*)x, row_start, deg, edge_src, (float4*)mean);
  sage_linear<<<grd_lin, blk, 0, stream>>>(x, mean, W1, b1, h1, 1);
  // Layer 2
  sage_aggregate<<<grd_agg, blk, 0, stream>>>(
      (const float4*)h1, row_start, deg, edge_src, (float4*)mean);
  sage_linear<<<grd_lin, blk, 0, stream>>>(h1, mean, W2, b2, out, 0);
}